// Round 9
// baseline (1310.796 us; speedup 1.0000x reference)
//
#include <hip/hip_runtime.h>
#include <hip/hip_bf16.h>
#include <stdint.h>

// ---------------- constants ----------------
#define TT 64
#define BB 32
#define NHIDC 768
#define NBK 6
#define BSZ 128
#define NTOKC 32000

using f32x4  = __attribute__((ext_vector_type(4))) float;
using f32x2  = __attribute__((ext_vector_type(2))) float;
using short8 = __attribute__((ext_vector_type(8))) short;

// ---------------- workspace layout (bytes) ----------------
#define OFF_FLG   0u           // [128] u32 flags
#define OFF_XPUB  4096u        // [2][16][6][2][132] f32 exchange
#define OFF_HTB   8065024u     // [64][32][768] bf16
#define OFF_K1    11210752u    // [64][32][64] f32
#define OFF_V1    11735040u    // [64][32][512] f32
#define OFF_U     15929344u    // [64][32][6][512] f32
#define OFF_WDB   41095168u    // [32000][768] bf16

__device__ __forceinline__ float sigf(float x){ return 1.f/(1.f + expf(-x)); }

// fine-grained MALL-coherent scalar ops — ONLY for the small per-step exchange.
__device__ __forceinline__ void stc(float* p, float v){
  __hip_atomic_store(p, v, __ATOMIC_RELAXED, __HIP_MEMORY_SCOPE_AGENT);
}
__device__ __forceinline__ float ldc(const float* p){
  return __hip_atomic_load(p, __ATOMIC_RELAXED, __HIP_MEMORY_SCOPE_AGENT);
}
#define VMCNT0 asm volatile("s_waitcnt vmcnt(0)" ::: "memory")
#define CBAR   asm volatile("" ::: "memory")

__device__ __forceinline__ void gload16(const void* g, void* l){
  __builtin_amdgcn_global_load_lds(
      (const __attribute__((address_space(1))) unsigned int*)g,
      (__attribute__((address_space(3))) unsigned int*)l, 16, 0, 0);
}

__device__ __forceinline__ int xslot(int par, int gg, int nn, int b){
  return (((par*16 + gg)*6 + nn)*2 + b)*132;
}

// ---------------- prep: reset flags + cast Wd->bf16 (vectorized) ----------------
__global__ void prep_kernel(const float* __restrict__ Wd,
                            unsigned short* __restrict__ Wdb,
                            unsigned int* __restrict__ flags)
{
  if (blockIdx.x == 0 && threadIdx.x < 128)
    __hip_atomic_store(flags + threadIdx.x, 0u, __ATOMIC_RELAXED, __HIP_MEMORY_SCOPE_AGENT);
  int i = blockIdx.x*blockDim.x + threadIdx.x;
  const int n4 = NTOKC*NHIDC/4;
  const int stride = gridDim.x*blockDim.x;
  for (; i < n4; i += stride){
    const float4 v = ((const float4*)Wd)[i];
    ushort4 o;
    __hip_bfloat16 b0 = __float2bfloat16(v.x); o.x = *reinterpret_cast<unsigned short*>(&b0);
    __hip_bfloat16 b1 = __float2bfloat16(v.y); o.y = *reinterpret_cast<unsigned short*>(&b1);
    __hip_bfloat16 b2 = __float2bfloat16(v.z); o.z = *reinterpret_cast<unsigned short*>(&b2);
    __hip_bfloat16 b3 = __float2bfloat16(v.w); o.w = *reinterpret_cast<unsigned short*>(&b3);
    ((ushort4*)Wdb)[i] = o;
  }
}

// ---------------- generic f32 tiled GEMM: C = A @ B ----------------
template<int TM, int TN>
__global__ __launch_bounds__(256) void gemm_f32(
    const float* __restrict__ A, int lda,
    const float* __restrict__ B, int ldb, long bstride,
    float* __restrict__ C, int ldc, long cstride,
    int N, int K)
{
  constexpr int BM = 16*TM, BN = 16*TN;
  __shared__ float As[16][BM];
  __shared__ float Bs[16][BN+4];
  const float* Bb = B + (long)blockIdx.z * bstride;
  float* Cb = C + (long)blockIdx.z * cstride;
  const int m0 = blockIdx.x*BM, n0 = blockIdx.y*BN;
  const int tid = threadIdx.x, tx = tid & 15, ty = tid >> 4;
  float acc[TM][TN];
  #pragma unroll
  for (int i=0;i<TM;++i)
    #pragma unroll
    for (int j=0;j<TN;++j) acc[i][j]=0.f;

  for (int k0=0; k0<K; k0+=16){
    if constexpr (TM == 8){
      const int r = tid>>1, kk = (tid&1)*8;
      const float4 v0 = *(const float4*)&A[(long)(m0+r)*lda + k0 + kk];
      const float4 v1 = *(const float4*)&A[(long)(m0+r)*lda + k0 + kk + 4];
      As[kk+0][r]=v0.x; As[kk+1][r]=v0.y; As[kk+2][r]=v0.z; As[kk+3][r]=v0.w;
      As[kk+4][r]=v1.x; As[kk+5][r]=v1.y; As[kk+6][r]=v1.z; As[kk+7][r]=v1.w;
    } else {
      const int r = tid>>2, kk = (tid&3)*4;
      const float4 v0 = *(const float4*)&A[(long)(m0+r)*lda + k0 + kk];
      As[kk+0][r]=v0.x; As[kk+1][r]=v0.y; As[kk+2][r]=v0.z; As[kk+3][r]=v0.w;
    }
    if constexpr (TN == 8){
      const int rb = tid>>4, cb = (tid&15)*8;
      float4 v0 = {0,0,0,0}, v1 = {0,0,0,0};
      if (n0+cb+4 <= N) v0 = *(const float4*)&Bb[(long)(k0+rb)*ldb + n0+cb];
      if (n0+cb+8 <= N) v1 = *(const float4*)&Bb[(long)(k0+rb)*ldb + n0+cb+4];
      *(float4*)&Bs[rb][cb]   = v0;
      *(float4*)&Bs[rb][cb+4] = v1;
    } else {
      const int rb = tid>>4, cb = (tid&15)*4;
      float4 v0 = {0,0,0,0};
      if (n0+cb+4 <= N) v0 = *(const float4*)&Bb[(long)(k0+rb)*ldb + n0+cb];
      *(float4*)&Bs[rb][cb] = v0;
    }
    __syncthreads();
    #pragma unroll
    for (int kk=0; kk<16; ++kk){
      float av[TM], bv[TN];
      #pragma unroll
      for (int i=0;i<TM;++i) av[i] = As[kk][ty*TM+i];
      #pragma unroll
      for (int j=0;j<TN;++j) bv[j] = Bs[kk][tx*TN+j];
      #pragma unroll
      for (int i=0;i<TM;++i)
        #pragma unroll
        for (int j=0;j<TN;++j) acc[i][j] += av[i]*bv[j];
    }
    __syncthreads();
  }
  #pragma unroll
  for (int i=0;i<TM;++i){
    const int row = m0 + ty*TM + i;
    #pragma unroll
    for (int j=0;j<TN;++j){
      const int col = n0 + tx*TN + j;
      if (col < N) Cb[(long)row*ldc + col] = acc[i][j];
    }
  }
}

// ---------------- persistent recurrent kernel ----------------
// 96 WGs x 1024 threads. WG w: group gg = w/6 (batches 2gg, 2gg+1), block n = w%6.
// R8 structure with: U prefetch -> LDS, fused gate-combine+pointwise, inline
// k2/v2 publish, and a single wave-local attention phase. 7 barriers/step.
__global__ __launch_bounds__(1024, 2) void recurrent_kernel(
    const float* __restrict__ hx0, const float* __restrict__ cx0,
    const float* __restrict__ Wq_in, const float* __restrict__ Whh,
    const float* __restrict__ b_lstm,
    const float* __restrict__ Wk_c, const float* __restrict__ Wv_c,
    const float* __restrict__ Wq_c, const float* __restrict__ Wo_c,
    const float* __restrict__ K1buf, const float* __restrict__ Ubuf,
    float* __restrict__ xpub, unsigned int* __restrict__ flags,
    unsigned short* __restrict__ HTx,
    float* __restrict__ out_hx, float* __restrict__ out_cx)
{
  const int w = blockIdx.x, gg = w/6, n = w - gg*6, tid = threadIdx.x;

  __shared__ float WcT[192*130];        // [c][h] transposed, c: k2|v2|q2
  __shared__ float WqL[128*65];         // [h][k] padded
  __shared__ float hL[2][128], cL[2][128], h0L[2][128], cnL[2][128];
  __shared__ float partL[2][2][512];    // [b][kh][c] gate partials
  __shared__ float uL[2][512];          // s-weighted U staging
  __shared__ float blL[512];
  __shared__ float kvqL[2][192];
  __shared__ float kvAll[2][6][130];
  __shared__ float commL[2][64];
  __shared__ float nullAll[2][8];
  __shared__ float sL[2], maskL[2];

  const int kh = tid >> 9, gc = tid & 511;   // gates: k-half, column
  const int od = tid >> 3, okq = tid & 7;    // Wo mapping

  // ---- Whh slice: 64 floats/thread, loaded once, pinned ----
  f32x4 whr[16];
  {
    const float* src = Whh + (long)n*65536 + kh*64*512 + gc;
    #pragma unroll
    for (int r4=0; r4<16; ++r4){
      f32x4 v;
      v[0] = src[(r4*4+0)*512]; v[1] = src[(r4*4+1)*512];
      v[2] = src[(r4*4+2)*512]; v[3] = src[(r4*4+3)*512];
      whr[r4] = v;
    }
  }
  #pragma unroll
  for (int i=0;i<16;++i) asm volatile("" : "+v"(whr[i]));
  // ---- Wo: 8 floats/thread, pinned ----
  f32x4 wo0, wo1;
  {
    const float* src = Wo_c + n*8192 + od;
    #pragma unroll
    for (int j=0;j<4;++j) wo0[j] = src[(okq*8+j)*128];
    #pragma unroll
    for (int j=0;j<4;++j) wo1[j] = src[(okq*8+4+j)*128];
  }
  asm volatile("" : "+v"(wo0));
  asm volatile("" : "+v"(wo1));

  if (tid < 512) blL[tid] = b_lstm[n*512 + tid];
  for (int i = tid; i < 8192; i += 1024){
    const int h = i>>6, c = i&63;
    WcT[(c    )*130 + h] = Wk_c[n*8192 + i];
    WcT[(c+ 64)*130 + h] = Wv_c[n*8192 + i];
    WcT[(c+128)*130 + h] = Wq_c[n*8192 + i];
    WqL[h*65 + c] = Wq_in[n*8192 + i];
  }
  if (tid < 256){
    const int b = tid>>7, d = tid&127;
    hL[b][d] = hx0[(gg*2+b)*768 + n*128 + d];
    cL[b][d] = cx0[(gg*2+b)*768 + n*128 + d];
  }
  __syncthreads();

  for (int t = 0; t < TT; ++t){
    const int par = t & 1;
    // ---- prefetch U -> LDS (thread (kh=b, gc=c)) + K1 -> reg ----
    uL[kh][gc] = Ubuf[((long)(t*32 + gg*2 + kh)*6 + n)*512 + gc];
    float k1r = 0.f;
    if (tid < 128) k1r = K1buf[(long)(t*32 + gg*2 + (tid>>6))*64 + (tid&63)];

    // A: gate partials (thread = (kh, col))
    {
      float gd0 = 0.f, gd1 = 0.f;
      #pragma unroll
      for (int r4 = 0; r4 < 16; ++r4){
        const f32x4 h0v = *(const f32x4*)&hL[0][kh*64 + r4*4];
        const f32x4 h1v = *(const f32x4*)&hL[1][kh*64 + r4*4];
        #pragma unroll
        for (int j=0;j<4;++j){
          gd0 += whr[r4][j]*h0v[j];
          gd1 += whr[r4][j]*h1v[j];
        }
      }
      partL[0][kh][gc] = gd0;
      partL[1][kh][gc] = gd1;
    }
    // B: q1 + input-softmax s; publish null immediately
    if (tid < 128){
      const int b = tid>>6, k = tid&63;
      float q = 0.f;
      #pragma unroll 16
      for (int h=0; h<128; ++h) q += WqL[h*65 + k]*hL[b][h];
      float term = q*k1r;
      #pragma unroll
      for (int off=32; off; off>>=1) term += __shfl_xor(term, off);
      if (k == 0){
        const float l1 = term*0.125f;
        const float mx = fmaxf(l1, 0.f);
        const float e0 = expf(0.f-mx), e1 = expf(l1-mx);
        const float inv = 1.f/(e0+e1);
        sL[b] = e1*inv;
        stc(&xpub[xslot(par,gg,n,b) + 128], e0*inv);
      }
    }
    __syncthreads();                                     // bar1
    // F: fused gate-combine + pointwise LSTM
    if (tid < 256){
      const int b = tid>>7, dd = tid&127;
      const float s = sL[b];
      const float gi = partL[b][0][dd]     + partL[b][1][dd]     + s*uL[b][dd]     + blL[dd];
      const float gf = partL[b][0][128+dd] + partL[b][1][128+dd] + s*uL[b][128+dd] + blL[128+dd];
      const float gG = partL[b][0][256+dd] + partL[b][1][256+dd] + s*uL[b][256+dd] + blL[256+dd];
      const float go = partL[b][0][384+dd] + partL[b][1][384+dd] + s*uL[b][384+dd] + blL[384+dd];
      const float cp = cL[b][dd];
      const float cn = sigf(gf)*cp + sigf(gi)*tanhf(gG);
      const float h0 = sigf(go)*tanhf(cn);
      cnL[b][dd] = cn; h0L[b][dd] = h0;
    }
    __syncthreads();                                     // bar2
    // H: kvq + inline publish of k2/v2
    if (tid < 384){
      const int b = tid/192, c = tid%192;
      float a = 0.f;
      #pragma unroll
      for (int h4=0; h4<32; ++h4){
        const f32x2 wa = *(const f32x2*)&WcT[c*130 + h4*4];
        const f32x2 wb = *(const f32x2*)&WcT[c*130 + h4*4 + 2];
        const f32x4 hv = *(const f32x4*)&h0L[b][h4*4];
        a += wa[0]*hv[0] + wa[1]*hv[1] + wb[0]*hv[2] + wb[1]*hv[3];
      }
      kvqL[b][c] = a;
      if (c < 128) stc(&xpub[xslot(par,gg,n,b) + c], a);
    }
    VMCNT0;
    __syncthreads();                                     // bar3
    if (tid < 6){
      if (tid == 0)
        __hip_atomic_store(&flags[gg*8+n], (unsigned)(t+1), __ATOMIC_RELAXED, __HIP_MEMORY_SCOPE_AGENT);
      while (__hip_atomic_load(&flags[gg*8+tid], __ATOMIC_RELAXED, __HIP_MEMORY_SCOPE_AGENT) < (unsigned)(t+1))
        __builtin_amdgcn_s_sleep(1);
    }
    __syncthreads(); CBAR;                               // bar4
    // L: stage all 6 blocks' k2/v2 + nulls into LDS
    for (int idx = tid; idx < 1536; idx += 1024){
      const int j = idx/256, r = idx&255, b = r>>7, c = r&127;
      kvAll[b][j][c] = ldc(&xpub[xslot(par,gg,j,b) + c]);
    }
    if (tid < 12){
      const int j = tid>>1, b = tid&1;
      nullAll[b][j] = ldc(&xpub[xslot(par,gg,j,b) + 128]);
    }
    __syncthreads();                                     // bar5
    // ATT: single wave does logits -> softmax -> PV -> mask, shuffle-local
    if (tid < 64){
      const int lane = tid;
      const int g5 = lane>>3, l3 = lane&7;
      const int b = g5>>2, h = g5&3;
      float lg = -1e30f;
      if (l3 < 6){
        float s = 0.f;
        #pragma unroll
        for (int kk=0; kk<16; ++kk)
          s += kvqL[b][128 + h*16 + kk]*kvAll[b][l3][h*16 + kk];
        lg = s*0.25f;
      }
      float mx = lg;
      mx = fmaxf(mx, __shfl_xor(mx,1));
      mx = fmaxf(mx, __shfl_xor(mx,2));
      mx = fmaxf(mx, __shfl_xor(mx,4));
      float ev = (l3 < 6) ? expf(lg - mx) : 0.f;
      float sum = ev;
      sum += __shfl_xor(sum,1); sum += __shfl_xor(sum,2); sum += __shfl_xor(sum,4);
      const float myw = ev/sum;
      float s0 = 0.f, s1 = 0.f;
      #pragma unroll
      for (int j=0;j<6;++j){
        const float wj = __shfl(myw, g5*8 + j);
        s0 += wj*kvAll[b][j][64 + h*16 + l3*2];
        s1 += wj*kvAll[b][j][64 + h*16 + l3*2 + 1];
      }
      commL[b][h*16 + l3*2]     = s0;
      commL[b][h*16 + l3*2 + 1] = s1;
      if (lane < 2){
        const float own = nullAll[lane][n];
        int rank = 0;
        #pragma unroll
        for (int j=0;j<6;++j){
          const float v = nullAll[lane][j];
          rank += (v > own || (v == own && j < n)) ? 1 : 0;
        }
        maskL[lane] = (rank < 2) ? 0.f : 1.f;
      }
    }
    __syncthreads();                                     // bar6
    // Q: Wo-reduce + masked state commit (8 threads per output dim)
    {
      #pragma unroll
      for (int b=0; b<2; ++b){
        float a = 0.f;
        #pragma unroll
        for (int j=0;j<4;++j) a += commL[b][okq*8+j]*wo0[j];
        #pragma unroll
        for (int j=0;j<4;++j) a += commL[b][okq*8+4+j]*wo1[j];
        a += __shfl_xor(a,1); a += __shfl_xor(a,2); a += __shfl_xor(a,4);
        if (okq == 0 && maskL[b] != 0.f){
          hL[b][od] = h0L[b][od] + a;
          cL[b][od] = cnL[b][od];
        }
      }
    }
    __syncthreads();                                     // bar7
    // R: HT (bf16) + final outputs (overlaps next step's prefetch/A/B)
    if (tid < 256){
      const int b = tid>>7, d = tid&127;
      const float hv = hL[b][d];
      __hip_bfloat16 hb16 = __float2bfloat16(hv);
      HTx[(long)(t*32 + gg*2 + b)*768 + n*128 + d] = *reinterpret_cast<unsigned short*>(&hb16);
      if (t == TT-1){
        out_hx[(gg*2+b)*768 + n*128 + d] = hv;
        out_cx[(gg*2+b)*768 + n*128 + d] = cL[b][d];
      }
    }
  }
}

// ---------------- decoder: out = HT @ Wd^T + bd, bf16 MFMA, XCD-swizzled ----------------
__global__ __launch_bounds__(256) void decoder_kernel(
    const unsigned short* __restrict__ A,   // [2048][768] bf16
    const unsigned short* __restrict__ Bw,  // [32000][768] bf16
    const float* __restrict__ bd,
    float* __restrict__ out)
{
  __shared__ unsigned short As[4096];  // [128][32]
  __shared__ unsigned short Bs[4096];  // [128][32]
  // bijective XCD swizzle: 4000 tiles = 8 XCDs x 500; each XCD owns a
  // contiguous tile range -> consecutive same-n0 tiles stay on one XCD's L2.
  const int bid = blockIdx.x;
  const int tile = (bid & 7)*500 + (bid >> 3);
  const int m0 = (tile & 15)*128, n0 = (tile >> 4)*128;
  const int tid = threadIdx.x;
  const int wv = tid >> 6, lane = tid & 63;
  const int wm = wv >> 1, wn = wv & 1;
  const int r16 = lane & 15, krow = lane >> 4;

  f32x4 acc[4][4] = {};

  for (int k0 = 0; k0 < 768; k0 += 32){
    #pragma unroll
    for (int i=0; i<2; ++i){
      const int idx = i*256 + tid;
      const int row = idx >> 2, k8 = (idx & 3)*8;
      gload16(&A [(long)(m0+row)*768 + k0 + k8], (char*)As + i*4096 + wv*1024);
      gload16(&Bw[(long)(n0+row)*768 + k0 + k8], (char*)Bs + i*4096 + wv*1024);
    }
    __syncthreads();
    short8 af[4], bf[4];
    #pragma unroll
    for (int mi=0; mi<4; ++mi)
      af[mi] = *(const short8*)&As[(wm*64 + mi*16 + r16)*32 + krow*8];
    #pragma unroll
    for (int ni=0; ni<4; ++ni)
      bf[ni] = *(const short8*)&Bs[(wn*64 + ni*16 + r16)*32 + krow*8];
    #pragma unroll
    for (int mi=0; mi<4; ++mi)
      #pragma unroll
      for (int ni=0; ni<4; ++ni)
        acc[mi][ni] = __builtin_amdgcn_mfma_f32_16x16x32_bf16(af[mi], bf[ni], acc[mi][ni], 0, 0, 0);
    __syncthreads();
  }

  #pragma unroll
  for (int ni=0; ni<4; ++ni){
    const int col = n0 + wn*64 + ni*16 + r16;
    const float bv = bd[col];
    #pragma unroll
    for (int mi=0; mi<4; ++mi){
      const int rbase = m0 + wm*64 + mi*16 + krow*4;
      #pragma unroll
      for (int j=0; j<4; ++j)
        out[(size_t)(rbase + j)*NTOKC + col] = acc[mi][ni][j] + bv;
    }
  }
}

// ---------------- launch ----------------
extern "C" void kernel_launch(void* const* d_in, const int* in_sizes, int n_in,
                              void* d_out, int out_size, void* d_ws, size_t ws_size,
                              hipStream_t stream)
{
  (void)in_sizes; (void)n_in; (void)out_size; (void)ws_size;
  const float* x      = (const float*)d_in[0];
  const float* hx0    = (const float*)d_in[1];
  const float* cx0    = (const float*)d_in[2];
  const float* Wq_in  = (const float*)d_in[3];
  const float* Wk_in  = (const float*)d_in[4];
  const float* Wv_in  = (const float*)d_in[5];
  const float* Wih    = (const float*)d_in[6];
  const float* Whh    = (const float*)d_in[7];
  const float* b_lstm = (const float*)d_in[8];
  const float* Wq_c   = (const float*)d_in[9];
  const float* Wk_c   = (const float*)d_in[10];
  const float* Wv_c   = (const float*)d_in[11];
  const float* Wo_c   = (const float*)d_in[12];
  const float* Wd     = (const float*)d_in[13];
  const float* bd     = (const float*)d_in[14];

  char* ws = (char*)d_ws;
  unsigned int*  flg  = (unsigned int*)(ws + OFF_FLG);
  float*         xpub = (float*)(ws + OFF_XPUB);
  unsigned short* HTx = (unsigned short*)(ws + OFF_HTB);
  float*         K1b  = (float*)(ws + OFF_K1);
  float*         V1b  = (float*)(ws + OFF_V1);
  float*         Ub   = (float*)(ws + OFF_U);
  unsigned short* Wdb = (unsigned short*)(ws + OFF_WDB);

  float* out_dec = (float*)d_out;
  float* out_hx  = out_dec + (size_t)2048*NTOKC;
  float* out_cx  = out_hx + BB*NHIDC;

  // 1) reset flags + Wd -> bf16
  prep_kernel<<<2048, 256, 0, stream>>>(Wd, Wdb, flg);
  // 2) K1 = x @ Wk_in[1]   (2048 x 64, K=768)
  gemm_f32<4,4><<<dim3(32,1,1), 256, 0, stream>>>(x, NHIDC, Wk_in + 768*64, 64, 0,
                                                  K1b, 64, 0, 64, NHIDC);
  // 3) V1 = x @ Wv_in[1]   (2048 x 512, K=768)
  gemm_f32<4,4><<<dim3(32,8,1), 256, 0, stream>>>(x, NHIDC, Wv_in + 768*512, 512, 0,
                                                  V1b, 512, 0, 512, NHIDC);
  // 4) U[:, n, :] = V1 @ Wih[n]  (2048 x 512 per n, K=512)
  gemm_f32<8,8><<<dim3(16,4,6), 256, 0, stream>>>(V1b, 512, Wih, 512, (long)512*512,
                                                  Ub, 3072, 512, 512, 512);
  // 5) recurrence: 96 WGs x 1024 threads, writes HTx bf16 directly
  recurrent_kernel<<<96, 1024, 0, stream>>>(hx0, cx0, Wq_in, Whh, b_lstm,
                                            Wk_c, Wv_c, Wq_c, Wo_c,
                                            K1b, Ub, xpub, flg, HTx,
                                            out_hx, out_cx);
  // 6) decoder GEMM + bias (XCD-swizzled 1D grid)
  decoder_kernel<<<4000, 256, 0, stream>>>(HTx, Wdb, bd, out_dec);
}

// Round 10
// 1273.494 us; speedup vs baseline: 1.0293x; 1.0293x over previous
//
#include <hip/hip_runtime.h>
#include <hip/hip_bf16.h>
#include <stdint.h>

// ---------------- constants ----------------
#define TT 64
#define BB 32
#define NHIDC 768
#define NBK 6
#define BSZ 128
#define NTOKC 32000

using f32x4  = __attribute__((ext_vector_type(4))) float;
using f32x2  = __attribute__((ext_vector_type(2))) float;
using short8 = __attribute__((ext_vector_type(8))) short;
typedef unsigned long long u64;

// ---------------- workspace layout (bytes) ----------------
#define OFF_XPUB  4096u        // [2][16][6][2][132] u64 tagged exchange (405,504 B)
#define OFF_HTB   8065024u     // [64][32][768] bf16
#define OFF_K1    11210752u    // [64][32][64] f32
#define OFF_V1    11735040u    // [64][32][512] f32
#define OFF_U     15929344u    // [64][32][6][512] f32
#define OFF_WDB   41095168u    // [32000][768] bf16

__device__ __forceinline__ float sigf(float x){ return 1.f/(1.f + expf(-x)); }

// tagged 8B MALL-coherent exchange ops: tag in hi32, f32 value in lo32.
__device__ __forceinline__ void stp(u64* p, float v, unsigned tag){
  union { float f; unsigned u; } cv; cv.f = v;
  const u64 pk = ((u64)tag << 32) | cv.u;
  __hip_atomic_store(p, pk, __ATOMIC_RELAXED, __HIP_MEMORY_SCOPE_AGENT);
}
__device__ __forceinline__ float ldp(const u64* p, unsigned tag){
  u64 v = __hip_atomic_load(p, __ATOMIC_RELAXED, __HIP_MEMORY_SCOPE_AGENT);
  while ((unsigned)(v >> 32) < tag){
    __builtin_amdgcn_s_sleep(1);
    v = __hip_atomic_load(p, __ATOMIC_RELAXED, __HIP_MEMORY_SCOPE_AGENT);
  }
  union { unsigned u; float f; } cv; cv.u = (unsigned)v;
  return cv.f;
}
#define CBAR asm volatile("" ::: "memory")

__device__ __forceinline__ void gload16(const void* g, void* l){
  __builtin_amdgcn_global_load_lds(
      (const __attribute__((address_space(1))) unsigned int*)g,
      (__attribute__((address_space(3))) unsigned int*)l, 16, 0, 0);
}

__device__ __forceinline__ int xslot(int par, int gg, int nn, int b){
  return (((par*16 + gg)*6 + nn)*2 + b)*132;
}

// ---------------- prep: zero exchange tags + cast Wd->bf16 (vectorized) ----------------
__global__ void prep_kernel(const float* __restrict__ Wd,
                            unsigned short* __restrict__ Wdb,
                            u64* __restrict__ xpub)
{
  // zero all tags so replay N+1 never sees a stale tag >= its poll target
  {
    int i = blockIdx.x*blockDim.x + threadIdx.x;
    const int nx = 2*16*6*2*132;
    const int stride = gridDim.x*blockDim.x;
    for (; i < nx; i += stride)
      __hip_atomic_store(xpub + i, 0ull, __ATOMIC_RELAXED, __HIP_MEMORY_SCOPE_AGENT);
  }
  int i = blockIdx.x*blockDim.x + threadIdx.x;
  const int n4 = NTOKC*NHIDC/4;
  const int stride = gridDim.x*blockDim.x;
  for (; i < n4; i += stride){
    const float4 v = ((const float4*)Wd)[i];
    ushort4 o;
    __hip_bfloat16 b0 = __float2bfloat16(v.x); o.x = *reinterpret_cast<unsigned short*>(&b0);
    __hip_bfloat16 b1 = __float2bfloat16(v.y); o.y = *reinterpret_cast<unsigned short*>(&b1);
    __hip_bfloat16 b2 = __float2bfloat16(v.z); o.z = *reinterpret_cast<unsigned short*>(&b2);
    __hip_bfloat16 b3 = __float2bfloat16(v.w); o.w = *reinterpret_cast<unsigned short*>(&b3);
    ((ushort4*)Wdb)[i] = o;
  }
}

// ---------------- generic f32 tiled GEMM: C = A @ B ----------------
template<int TM, int TN>
__global__ __launch_bounds__(256) void gemm_f32(
    const float* __restrict__ A, int lda,
    const float* __restrict__ B, int ldb, long bstride,
    float* __restrict__ C, int ldc, long cstride,
    int N, int K)
{
  constexpr int BM = 16*TM, BN = 16*TN;
  __shared__ float As[16][BM];
  __shared__ float Bs[16][BN+4];
  const float* Bb = B + (long)blockIdx.z * bstride;
  float* Cb = C + (long)blockIdx.z * cstride;
  const int m0 = blockIdx.x*BM, n0 = blockIdx.y*BN;
  const int tid = threadIdx.x, tx = tid & 15, ty = tid >> 4;
  float acc[TM][TN];
  #pragma unroll
  for (int i=0;i<TM;++i)
    #pragma unroll
    for (int j=0;j<TN;++j) acc[i][j]=0.f;

  for (int k0=0; k0<K; k0+=16){
    if constexpr (TM == 8){
      const int r = tid>>1, kk = (tid&1)*8;
      const float4 v0 = *(const float4*)&A[(long)(m0+r)*lda + k0 + kk];
      const float4 v1 = *(const float4*)&A[(long)(m0+r)*lda + k0 + kk + 4];
      As[kk+0][r]=v0.x; As[kk+1][r]=v0.y; As[kk+2][r]=v0.z; As[kk+3][r]=v0.w;
      As[kk+4][r]=v1.x; As[kk+5][r]=v1.y; As[kk+6][r]=v1.z; As[kk+7][r]=v1.w;
    } else {
      const int r = tid>>2, kk = (tid&3)*4;
      const float4 v0 = *(const float4*)&A[(long)(m0+r)*lda + k0 + kk];
      As[kk+0][r]=v0.x; As[kk+1][r]=v0.y; As[kk+2][r]=v0.z; As[kk+3][r]=v0.w;
    }
    if constexpr (TN == 8){
      const int rb = tid>>4, cb = (tid&15)*8;
      float4 v0 = {0,0,0,0}, v1 = {0,0,0,0};
      if (n0+cb+4 <= N) v0 = *(const float4*)&Bb[(long)(k0+rb)*ldb + n0+cb];
      if (n0+cb+8 <= N) v1 = *(const float4*)&Bb[(long)(k0+rb)*ldb + n0+cb+4];
      *(float4*)&Bs[rb][cb]   = v0;
      *(float4*)&Bs[rb][cb+4] = v1;
    } else {
      const int rb = tid>>4, cb = (tid&15)*4;
      float4 v0 = {0,0,0,0};
      if (n0+cb+4 <= N) v0 = *(const float4*)&Bb[(long)(k0+rb)*ldb + n0+cb];
      *(float4*)&Bs[rb][cb] = v0;
    }
    __syncthreads();
    #pragma unroll
    for (int kk=0; kk<16; ++kk){
      float av[TM], bv[TN];
      #pragma unroll
      for (int i=0;i<TM;++i) av[i] = As[kk][ty*TM+i];
      #pragma unroll
      for (int j=0;j<TN;++j) bv[j] = Bs[kk][tx*TN+j];
      #pragma unroll
      for (int i=0;i<TM;++i)
        #pragma unroll
        for (int j=0;j<TN;++j) acc[i][j] += av[i]*bv[j];
    }
    __syncthreads();
  }
  #pragma unroll
  for (int i=0;i<TM;++i){
    const int row = m0 + ty*TM + i;
    #pragma unroll
    for (int j=0;j<TN;++j){
      const int col = n0 + tx*TN + j;
      if (col < N) Cb[(long)row*ldc + col] = acc[i][j];
    }
  }
}

// ---------------- persistent recurrent kernel ----------------
// 96 WGs x 1024 threads. WG w: group gg = w/6 (batches 2gg, 2gg+1), block n = w%6.
// Exchange = tagged 8B atomics: readers poll directly on the data (tag>=t+1),
// publisher never stalls. No flags, no vmcnt(0), 6 barriers/step.
__global__ __launch_bounds__(1024, 2) void recurrent_kernel(
    const float* __restrict__ hx0, const float* __restrict__ cx0,
    const float* __restrict__ Wq_in, const float* __restrict__ Whh,
    const float* __restrict__ b_lstm,
    const float* __restrict__ Wk_c, const float* __restrict__ Wv_c,
    const float* __restrict__ Wq_c, const float* __restrict__ Wo_c,
    const float* __restrict__ K1buf, const float* __restrict__ Ubuf,
    u64* __restrict__ xpub,
    unsigned short* __restrict__ HTx,
    float* __restrict__ out_hx, float* __restrict__ out_cx)
{
  const int w = blockIdx.x, gg = w/6, n = w - gg*6, tid = threadIdx.x;

  __shared__ float WcT[192*130];        // [c][h] transposed, c: k2|v2|q2
  __shared__ float WqL[128*65];         // [h][k] padded
  __shared__ float hL[2][128], cL[2][128], h0L[2][128], cnL[2][128];
  __shared__ float partL[2][2][512];    // [b][kh][c] gate partials
  __shared__ float uL[2][512];
  __shared__ float blL[512];
  __shared__ float kvqL[2][192];
  __shared__ float kvAll[2][6][130];
  __shared__ float commL[2][64];
  __shared__ float nullAll[2][8];
  __shared__ float sL[2], nullLoc[2], maskL[2];

  const int kh = tid >> 9, gc = tid & 511;   // gates: k-half, column
  const int od = tid >> 3, okq = tid & 7;    // Wo mapping

  // ---- Whh slice: 64 floats/thread, loaded once, pinned ----
  f32x4 whr[16];
  {
    const float* src = Whh + (long)n*65536 + kh*64*512 + gc;
    #pragma unroll
    for (int r4=0; r4<16; ++r4){
      f32x4 v;
      v[0] = src[(r4*4+0)*512]; v[1] = src[(r4*4+1)*512];
      v[2] = src[(r4*4+2)*512]; v[3] = src[(r4*4+3)*512];
      whr[r4] = v;
    }
  }
  #pragma unroll
  for (int i=0;i<16;++i) asm volatile("" : "+v"(whr[i]));
  // ---- Wo: 8 floats/thread, pinned ----
  f32x4 wo0, wo1;
  {
    const float* src = Wo_c + n*8192 + od;
    #pragma unroll
    for (int j=0;j<4;++j) wo0[j] = src[(okq*8+j)*128];
    #pragma unroll
    for (int j=0;j<4;++j) wo1[j] = src[(okq*8+4+j)*128];
  }
  asm volatile("" : "+v"(wo0));
  asm volatile("" : "+v"(wo1));

  if (tid < 512) blL[tid] = b_lstm[n*512 + tid];
  for (int i = tid; i < 8192; i += 1024){
    const int h = i>>6, c = i&63;
    WcT[(c    )*130 + h] = Wk_c[n*8192 + i];
    WcT[(c+ 64)*130 + h] = Wv_c[n*8192 + i];
    WcT[(c+128)*130 + h] = Wq_c[n*8192 + i];
    WqL[h*65 + c] = Wq_in[n*8192 + i];
  }
  if (tid < 256){
    const int b = tid>>7, d = tid&127;
    hL[b][d] = hx0[(gg*2+b)*768 + n*128 + d];
    cL[b][d] = cx0[(gg*2+b)*768 + n*128 + d];
  }
  __syncthreads();

  for (int t = 0; t < TT; ++t){
    const int par = t & 1;
    const unsigned tag = (unsigned)(t+1);
    // ---- prefetch U -> LDS + K1 -> reg ----
    uL[kh][gc] = Ubuf[((long)(t*32 + gg*2 + kh)*6 + n)*512 + gc];
    float k1r = 0.f;
    if (tid < 128) k1r = K1buf[(long)(t*32 + gg*2 + (tid>>6))*64 + (tid&63)];

    // A: gate partials (thread = (kh, col))
    {
      float gd0 = 0.f, gd1 = 0.f;
      #pragma unroll
      for (int r4 = 0; r4 < 16; ++r4){
        const f32x4 h0v = *(const f32x4*)&hL[0][kh*64 + r4*4];
        const f32x4 h1v = *(const f32x4*)&hL[1][kh*64 + r4*4];
        #pragma unroll
        for (int j=0;j<4;++j){
          gd0 += whr[r4][j]*h0v[j];
          gd1 += whr[r4][j]*h1v[j];
        }
      }
      partL[0][kh][gc] = gd0;
      partL[1][kh][gc] = gd1;
    }
    // B: q1 + input-softmax s; publish tagged null immediately (no wait)
    if (tid < 128){
      const int b = tid>>6, k = tid&63;
      float q = 0.f;
      #pragma unroll 16
      for (int h=0; h<128; ++h) q += WqL[h*65 + k]*hL[b][h];
      float term = q*k1r;
      #pragma unroll
      for (int off=32; off; off>>=1) term += __shfl_xor(term, off);
      if (k == 0){
        const float l1 = term*0.125f;
        const float mx = fmaxf(l1, 0.f);
        const float e0 = expf(0.f-mx), e1 = expf(l1-mx);
        const float inv = 1.f/(e0+e1);
        sL[b] = e1*inv;
        nullLoc[b] = e0*inv;
        stp(xpub + xslot(par,gg,n,b) + 128, e0*inv, tag);
      }
    }
    __syncthreads();                                     // bar1
    // F: fused gate-combine + pointwise LSTM
    if (tid < 256){
      const int b = tid>>7, dd = tid&127;
      const float s = sL[b];
      const float gi = partL[b][0][dd]     + partL[b][1][dd]     + s*uL[b][dd]     + blL[dd];
      const float gf = partL[b][0][128+dd] + partL[b][1][128+dd] + s*uL[b][128+dd] + blL[128+dd];
      const float gG = partL[b][0][256+dd] + partL[b][1][256+dd] + s*uL[b][256+dd] + blL[256+dd];
      const float go = partL[b][0][384+dd] + partL[b][1][384+dd] + s*uL[b][384+dd] + blL[384+dd];
      const float cp = cL[b][dd];
      const float cn = sigf(gf)*cp + sigf(gi)*tanhf(gG);
      const float h0 = sigf(go)*tanhf(cn);
      cnL[b][dd] = cn; h0L[b][dd] = h0;
    }
    __syncthreads();                                     // bar2
    // H: kvq + inline tagged publish of k2/v2 (no wait)
    if (tid < 384){
      const int b = tid/192, c = tid%192;
      float a = 0.f;
      #pragma unroll
      for (int h4=0; h4<32; ++h4){
        const f32x2 wa = *(const f32x2*)&WcT[c*130 + h4*4];
        const f32x2 wb = *(const f32x2*)&WcT[c*130 + h4*4 + 2];
        const f32x4 hv = *(const f32x4*)&h0L[b][h4*4];
        a += wa[0]*hv[0] + wa[1]*hv[1] + wb[0]*hv[2] + wb[1]*hv[3];
      }
      kvqL[b][c] = a;
      if (c < 128) stp(xpub + xslot(par,gg,n,b) + c, a, tag);
    }
    __syncthreads();                                     // bar3
    // L: gather peers' k2/v2 + nulls by polling tagged data directly
    for (int idx = tid; idx < 1536; idx += 1024){
      const int j = idx/256, r = idx&255, b = r>>7, c = r&127;
      if (j == n) kvAll[b][j][c] = kvqL[b][c];
      else        kvAll[b][j][c] = ldp(xpub + xslot(par,gg,j,b) + c, tag);
    }
    if (tid < 12){
      const int j = tid>>1, b = tid&1;
      if (j == n) nullAll[b][j] = nullLoc[b];
      else        nullAll[b][j] = ldp(xpub + xslot(par,gg,j,b) + 128, tag);
    }
    __syncthreads(); CBAR;                               // bar4
    // ATT: single wave does logits -> softmax -> PV -> mask, shuffle-local
    if (tid < 64){
      const int lane = tid;
      const int g5 = lane>>3, l3 = lane&7;
      const int b = g5>>2, h = g5&3;
      float lg = -1e30f;
      if (l3 < 6){
        float s = 0.f;
        #pragma unroll
        for (int kk=0; kk<16; ++kk)
          s += kvqL[b][128 + h*16 + kk]*kvAll[b][l3][h*16 + kk];
        lg = s*0.25f;
      }
      float mx = lg;
      mx = fmaxf(mx, __shfl_xor(mx,1));
      mx = fmaxf(mx, __shfl_xor(mx,2));
      mx = fmaxf(mx, __shfl_xor(mx,4));
      float ev = (l3 < 6) ? expf(lg - mx) : 0.f;
      float sum = ev;
      sum += __shfl_xor(sum,1); sum += __shfl_xor(sum,2); sum += __shfl_xor(sum,4);
      const float myw = ev/sum;
      float s0 = 0.f, s1 = 0.f;
      #pragma unroll
      for (int j=0;j<6;++j){
        const float wj = __shfl(myw, g5*8 + j);
        s0 += wj*kvAll[b][j][64 + h*16 + l3*2];
        s1 += wj*kvAll[b][j][64 + h*16 + l3*2 + 1];
      }
      commL[b][h*16 + l3*2]     = s0;
      commL[b][h*16 + l3*2 + 1] = s1;
      if (lane < 2){
        const float own = nullAll[lane][n];
        int rank = 0;
        #pragma unroll
        for (int j=0;j<6;++j){
          const float v = nullAll[lane][j];
          rank += (v > own || (v == own && j < n)) ? 1 : 0;
        }
        maskL[lane] = (rank < 2) ? 0.f : 1.f;
      }
    }
    __syncthreads();                                     // bar5
    // Q: Wo-reduce + masked state commit (8 threads per output dim)
    {
      #pragma unroll
      for (int b=0; b<2; ++b){
        float a = 0.f;
        #pragma unroll
        for (int j=0;j<4;++j) a += commL[b][okq*8+j]*wo0[j];
        #pragma unroll
        for (int j=0;j<4;++j) a += commL[b][okq*8+4+j]*wo1[j];
        a += __shfl_xor(a,1); a += __shfl_xor(a,2); a += __shfl_xor(a,4);
        if (okq == 0 && maskL[b] != 0.f){
          hL[b][od] = h0L[b][od] + a;
          cL[b][od] = cnL[b][od];
        }
      }
    }
    __syncthreads();                                     // bar6
    // R: HT (bf16) + final outputs (overlaps next step's prefetch/A/B)
    if (tid < 256){
      const int b = tid>>7, d = tid&127;
      const float hv = hL[b][d];
      __hip_bfloat16 hb16 = __float2bfloat16(hv);
      HTx[(long)(t*32 + gg*2 + b)*768 + n*128 + d] = *reinterpret_cast<unsigned short*>(&hb16);
      if (t == TT-1){
        out_hx[(gg*2+b)*768 + n*128 + d] = hv;
        out_cx[(gg*2+b)*768 + n*128 + d] = cL[b][d];
      }
    }
  }
}

// ---------------- decoder: out = HT @ Wd^T + bd, bf16 MFMA, XCD-swizzled ----------------
__global__ __launch_bounds__(256) void decoder_kernel(
    const unsigned short* __restrict__ A,   // [2048][768] bf16
    const unsigned short* __restrict__ Bw,  // [32000][768] bf16
    const float* __restrict__ bd,
    float* __restrict__ out)
{
  __shared__ unsigned short As[4096];  // [128][32]
  __shared__ unsigned short Bs[4096];  // [128][32]
  const int bid = blockIdx.x;
  const int tile = (bid & 7)*500 + (bid >> 3);
  const int m0 = (tile & 15)*128, n0 = (tile >> 4)*128;
  const int tid = threadIdx.x;
  const int wv = tid >> 6, lane = tid & 63;
  const int wm = wv >> 1, wn = wv & 1;
  const int r16 = lane & 15, krow = lane >> 4;

  f32x4 acc[4][4] = {};

  for (int k0 = 0; k0 < 768; k0 += 32){
    #pragma unroll
    for (int i=0; i<2; ++i){
      const int idx = i*256 + tid;
      const int row = idx >> 2, k8 = (idx & 3)*8;
      gload16(&A [(long)(m0+row)*768 + k0 + k8], (char*)As + i*4096 + wv*1024);
      gload16(&Bw[(long)(n0+row)*768 + k0 + k8], (char*)Bs + i*4096 + wv*1024);
    }
    __syncthreads();
    short8 af[4], bf[4];
    #pragma unroll
    for (int mi=0; mi<4; ++mi)
      af[mi] = *(const short8*)&As[(wm*64 + mi*16 + r16)*32 + krow*8];
    #pragma unroll
    for (int ni=0; ni<4; ++ni)
      bf[ni] = *(const short8*)&Bs[(wn*64 + ni*16 + r16)*32 + krow*8];
    #pragma unroll
    for (int mi=0; mi<4; ++mi)
      #pragma unroll
      for (int ni=0; ni<4; ++ni)
        acc[mi][ni] = __builtin_amdgcn_mfma_f32_16x16x32_bf16(af[mi], bf[ni], acc[mi][ni], 0, 0, 0);
    __syncthreads();
  }

  #pragma unroll
  for (int ni=0; ni<4; ++ni){
    const int col = n0 + wn*64 + ni*16 + r16;
    const float bv = bd[col];
    #pragma unroll
    for (int mi=0; mi<4; ++mi){
      const int rbase = m0 + wm*64 + mi*16 + krow*4;
      #pragma unroll
      for (int j=0; j<4; ++j)
        out[(size_t)(rbase + j)*NTOKC + col] = acc[mi][ni][j] + bv;
    }
  }
}

// ---------------- launch ----------------
extern "C" void kernel_launch(void* const* d_in, const int* in_sizes, int n_in,
                              void* d_out, int out_size, void* d_ws, size_t ws_size,
                              hipStream_t stream)
{
  (void)in_sizes; (void)n_in; (void)out_size; (void)ws_size;
  const float* x      = (const float*)d_in[0];
  const float* hx0    = (const float*)d_in[1];
  const float* cx0    = (const float*)d_in[2];
  const float* Wq_in  = (const float*)d_in[3];
  const float* Wk_in  = (const float*)d_in[4];
  const float* Wv_in  = (const float*)d_in[5];
  const float* Wih    = (const float*)d_in[6];
  const float* Whh    = (const float*)d_in[7];
  const float* b_lstm = (const float*)d_in[8];
  const float* Wq_c   = (const float*)d_in[9];
  const float* Wk_c   = (const float*)d_in[10];
  const float* Wv_c   = (const float*)d_in[11];
  const float* Wo_c   = (const float*)d_in[12];
  const float* Wd     = (const float*)d_in[13];
  const float* bd     = (const float*)d_in[14];

  char* ws = (char*)d_ws;
  u64*           xpub = (u64*)(ws + OFF_XPUB);
  unsigned short* HTx = (unsigned short*)(ws + OFF_HTB);
  float*         K1b  = (float*)(ws + OFF_K1);
  float*         V1b  = (float*)(ws + OFF_V1);
  float*         Ub   = (float*)(ws + OFF_U);
  unsigned short* Wdb = (unsigned short*)(ws + OFF_WDB);

  float* out_dec = (float*)d_out;
  float* out_hx  = out_dec + (size_t)2048*NTOKC;
  float* out_cx  = out_hx + BB*NHIDC;

  // 1) zero exchange tags + Wd -> bf16
  prep_kernel<<<2048, 256, 0, stream>>>(Wd, Wdb, xpub);
  // 2) K1 = x @ Wk_in[1]   (2048 x 64, K=768)
  gemm_f32<4,4><<<dim3(32,1,1), 256, 0, stream>>>(x, NHIDC, Wk_in + 768*64, 64, 0,
                                                  K1b, 64, 0, 64, NHIDC);
  // 3) V1 = x @ Wv_in[1]   (2048 x 512, K=768)
  gemm_f32<4,4><<<dim3(32,8,1), 256, 0, stream>>>(x, NHIDC, Wv_in + 768*512, 512, 0,
                                                  V1b, 512, 0, 512, NHIDC);
  // 4) U[:, n, :] = V1 @ Wih[n]  (2048 x 512 per n, K=512)
  gemm_f32<8,8><<<dim3(16,4,6), 256, 0, stream>>>(V1b, 512, Wih, 512, (long)512*512,
                                                  Ub, 3072, 512, 512, 512);
  // 5) recurrence: 96 WGs x 1024 threads, writes HTx bf16 directly
  recurrent_kernel<<<96, 1024, 0, stream>>>(hx0, cx0, Wq_in, Whh, b_lstm,
                                            Wk_c, Wv_c, Wq_c, Wo_c,
                                            K1b, Ub, xpub, HTx,
                                            out_hx, out_cx);
  // 6) decoder GEMM + bias (XCD-swizzled 1D grid)
  decoder_kernel<<<4000, 256, 0, stream>>>(HTx, Wdb, bd, out_dec);
}